// Round 1
// 2157.407 us; speedup vs baseline: 1.5851x; 1.5851x over previous
//
#include <hip/hip_runtime.h>

// 16-qubit statevector, 512 samples, 6 StronglyEntanglingLayers, qubit q <-> bit q.
// Round 8: ZERO cross-wave exchanges. Gate schedule (r = l+1):
//   P(l) tile bits 0-12, fixed 13-15; local={0,10,11,12}, lane={4..9}(tid0-5),
//        wave={1,2,3}(tid6-8). Does R_l(4..12) + ring prefix g in [gs, 11-l],
//        gs = {3,2,1,0,0,0}: targets all in {4..12} => lane/local only.
//   Q(l) tile bits 0-6,10-15, fixed 7-9; local={0,1,2,3}, lane={4,5,6}(tid0-2)
//        +{13,14,15}(tid3-5), wave={10,11,12}(tid6-8). Does R_l(13..15) (lane),
//        ring suffix g in [12-l, 15] (targets {13,14,15}U{0..r-1} => lane/local;
//        controls >=7 => thread-uniform), then HEAD of layer l+1: R_{l+1}(0..3)
//        (local) and early CNOTs with wires<=3 (layer1: (0,2),(1,3); layer2: (0,3)).
//   P(0): init = product of v_q = Rot_0(q)*RX(x_q)|0> with the first chain
//        (0,1),(1,2),(2,3) folded as a basis permutation (c=(b0,b0^b1,b1^b2,b2^b3)).
//   Q(5): fused measurement -> per-block partials, reduced by reduceK. No store.
// Per-wire ordering vs ring order verified gate-by-gate (see session journal).

#define NTH 512
typedef float v16f __attribute__((ext_vector_type(16)));

template <int I> struct IC { static constexpr int value = I; };
template <int N, int I = 0, typename F>
__device__ __forceinline__ void static_for(F&& f) {
  if constexpr (I < N) { f(IC<I>{}); static_for<N, I + 1>(f); }
}

// element e -> in-tile local offset bits. SH=1: identity (Q). SH=10: bit0 + bits10-12 (P).
template <int SH, int E> struct EIdx { static constexpr int v = (E & 1) | ((E >> 1) << SH); };

// ---------------- gate helpers on 16 reg amps ----------------

template <int LB>  // Rot on local e-bit LB
__device__ __forceinline__ void rot_local(v16f& ar, v16f& ai, const float* __restrict__ u) {
  const float u00r = u[0], u00i = u[1], u01r = u[2], u01i = u[3];
  const float u10r = u[4], u10i = u[5], u11r = u[6], u11i = u[7];
  static_for<8>([&](auto hc) {
    constexpr int h = hc.value;
    constexpr int e0 = ((h >> LB) << (LB + 1)) | (h & ((1 << LB) - 1));
    constexpr int e1 = e0 | (1 << LB);
    const float axr = ar[e0], axi = ai[e0], bxr = ar[e1], bxi = ai[e1];
    ar[e0] = u00r * axr - u00i * axi + u01r * bxr - u01i * bxi;
    ai[e0] = u00r * axi + u00i * axr + u01r * bxi + u01i * bxr;
    ar[e1] = u10r * axr - u10i * axi + u11r * bxr - u11i * bxi;
    ai[e1] = u10r * axi + u10i * axr + u11r * bxi + u11i * bxr;
  });
}

// Rot on a lane bit: shfl mask m, bit = this lane's bit value
__device__ __forceinline__ void rot_lane(v16f& ar, v16f& ai, const float* __restrict__ u,
                                         const int m, const int bit) {
  const float car = bit ? u[6] : u[0], cai = bit ? u[7] : u[1];
  const float cbr = bit ? u[4] : u[2], cbi = bit ? u[5] : u[3];
  static_for<16>([&](auto ec) {
    constexpr int e = ec.value;
    const float orr = ar[e], oii = ai[e];
    const float pr = __shfl_xor(orr, m);
    const float pi = __shfl_xor(oii, m);
    ar[e] = car * orr - cai * oii + cbr * pr - cbi * pi;
    ai[e] = car * oii + cai * orr + cbr * pi + cbi * pr;
  });
}

// CNOT, lane-bit target (shfl mask m), control amp-bit C (compile-time).
// If C is a local bit: per-element static participation (half the elements swap).
// Else: thread-uniform take from ibase -> branch (wave-bit controls skip whole waves;
// lane-bit controls run masked; partner lanes always have equal take since C != t).
template <int SH, int C>
__device__ __forceinline__ void cnot_lane(v16f& ar, v16f& ai, const int m, const int ibase) {
  if constexpr ((EIdx<SH, 15>::v >> C) & 1) {
    static_for<16>([&](auto ec) {
      constexpr int e = ec.value;
      if constexpr ((EIdx<SH, e>::v >> C) & 1) {
        ar[e] = __shfl_xor(ar[e], m);
        ai[e] = __shfl_xor(ai[e], m);
      }
    });
  } else {
    if ((ibase >> C) & 1) {
      static_for<16>([&](auto ec) {
        constexpr int e = ec.value;
        ar[e] = __shfl_xor(ar[e], m);
        ai[e] = __shfl_xor(ai[e], m);
      });
    }
  }
}

// CNOT, local e-bit target TB, control amp-bit C (compile-time, C != target bit).
template <int TB, int SH, int C>
__device__ __forceinline__ void cnot_local(v16f& ar, v16f& ai, const int ibase) {
  static_for<8>([&](auto hc) {
    constexpr int h = hc.value;
    constexpr int e0 = ((h >> TB) << (TB + 1)) | (h & ((1 << TB) - 1));
    constexpr int e1 = e0 | (1 << TB);
    if constexpr ((EIdx<SH, 15>::v >> C) & 1) {
      if constexpr ((EIdx<SH, e0>::v >> C) & 1) {  // static: pure register swap
        const float tr = ar[e0], ti = ai[e0];
        ar[e0] = ar[e1]; ai[e0] = ai[e1];
        ar[e1] = tr;     ai[e1] = ti;
      }
    } else {
      const int take = (ibase >> C) & 1;
      const float axr = ar[e0], axi = ai[e0], bxr = ar[e1], bxi = ai[e1];
      ar[e0] = take ? bxr : axr; ai[e0] = take ? bxi : axi;
      ar[e1] = take ? axr : bxr; ai[e1] = take ? axi : bxi;
    }
  });
}

// ---------------- prep: 96 Rot matrices ----------------
__global__ void qsim_prep(const float* __restrict__ w, float* __restrict__ gm) {
  const int i = threadIdx.x;
  if (i < 96) {
    const float phi = w[i * 3 + 0];
    const float th  = w[i * 3 + 1];
    const float om  = w[i * 3 + 2];
    float st, ct; sincosf(0.5f * th, &st, &ct);
    float sa, ca; sincosf(0.5f * (phi + om), &sa, &ca);
    float sb, cb; sincosf(0.5f * (phi - om), &sb, &cb);
    float* u = gm + i * 8;
    u[0] =  ct * ca; u[1] = -ct * sa;   // m00
    u[2] = -st * cb; u[3] = -st * sb;   // m01
    u[4] =  st * cb; u[5] = -st * sb;   // m10
    u[6] =  ct * ca; u[7] =  ct * sa;   // m11
  }
}

// ---------------- Sweep P ----------------
template <int L>
__global__ void __launch_bounds__(NTH) sweepP(float2* __restrict__ st,
                                              const float* __restrict__ x,
                                              const float* __restrict__ gm) {
  const int tid = threadIdx.x;
  const int s  = blockIdx.x >> 3;
  const int fb = blockIdx.x & 7;
  // amp bits: 0,10,11,12 local | 4..9 = tid0-5 | 1,2,3 = tid6-8 | 13..15 = fb
  const int ibase = (fb << 13) | ((tid & 63) << 4) | ((tid >> 6) << 1);
  float2* __restrict__ base = st + (s << 16) + ibase;
  constexpr int r = L + 1;
  const float* __restrict__ gl = gm + L * 128;
  v16f ar, ai;

  if constexpr (L == 0) {
    // init: product of v_q = Rot_0(q) * RX(x_q)|0>, with CNOT chain (0,1),(1,2),(2,3) folded.
    __shared__ float iv[16][4];
    if (tid < 16) {
      const float* u = gm + tid * 8;
      float sx, cx; sincosf(0.5f * x[s * 16 + tid], &sx, &cx);
      iv[tid][0] = u[0] * cx + u[3] * sx;   // v0r
      iv[tid][1] = u[1] * cx - u[2] * sx;   // v0i
      iv[tid][2] = u[4] * cx + u[7] * sx;   // v1r
      iv[tid][3] = u[5] * cx - u[6] * sx;   // v1i
    }
    __syncthreads();
    // thread-uniform factor over bits 4..9 (tid) and 13..15 (fb)
    float Tr = 1.f, Ti = 0.f;
    #pragma unroll
    for (int b = 4; b <= 9; ++b) {
      const int bit = (ibase >> b) & 1;
      const float fr = iv[b][2 * bit], fi = iv[b][2 * bit + 1];
      const float nr = Tr * fr - Ti * fi; Ti = Tr * fi + Ti * fr; Tr = nr;
    }
    #pragma unroll
    for (int b = 13; b <= 15; ++b) {
      const int bit = (ibase >> b) & 1;
      const float fr = iv[b][2 * bit], fi = iv[b][2 * bit + 1];
      const float nr = Tr * fr - Ti * fi; Ti = Tr * fi + Ti * fr; Tr = nr;
    }
    // W(b0) over qubits 0..3 with chain permutation preimage c=(b0,b0^b1,b1^b2,b2^b3)
    const int b1 = (ibase >> 1) & 1, b2 = (ibase >> 2) & 1, b3 = (ibase >> 3) & 1;
    float Wr[2], Wi[2];
    #pragma unroll
    for (int b0 = 0; b0 < 2; ++b0) {
      const int c1 = b0 ^ b1, c2 = b1 ^ b2, c3 = b2 ^ b3;
      float wr = iv[0][2 * b0], wi = iv[0][2 * b0 + 1];
      { const float fr = iv[1][2 * c1], fi = iv[1][2 * c1 + 1];
        const float nr = wr * fr - wi * fi; wi = wr * fi + wi * fr; wr = nr; }
      { const float fr = iv[2][2 * c2], fi = iv[2][2 * c2 + 1];
        const float nr = wr * fr - wi * fi; wi = wr * fi + wi * fr; wr = nr; }
      { const float fr = iv[3][2 * c3], fi = iv[3][2 * c3 + 1];
        const float nr = wr * fr - wi * fi; wi = wr * fi + wi * fr; wr = nr; }
      Wr[b0] = wr * Tr - wi * Ti; Wi[b0] = wr * Ti + wi * Tr;
    }
    ar[0] = Wr[0]; ai[0] = Wi[0]; ar[1] = Wr[1]; ai[1] = Wi[1];
    // expand local e-bits 1..3 = qubits 10,11,12
    static_for<3>([&](auto bc) {
      constexpr int bI = bc.value;
      const int q = 10 + bI;
      const float v0r = iv[q][0], v0i = iv[q][1], v1r = iv[q][2], v1i = iv[q][3];
      static_for<(1 << (bI + 1))>([&](auto kc) {
        constexpr int k = kc.value;
        constexpr int k1 = k | (1 << (bI + 1));
        const float kr = ar[k], ki = ai[k];
        ar[k1] = kr * v1r - ki * v1i; ai[k1] = kr * v1i + ki * v1r;
        ar[k]  = kr * v0r - ki * v0i; ai[k]  = kr * v0i + ki * v0r;
      });
    });
  } else {
    #pragma unroll
    for (int eh = 0; eh < 8; ++eh) {
      const float4 v = *reinterpret_cast<const float4*>(base + (eh << 10));
      ar[2 * eh] = v.x; ai[2 * eh] = v.y; ar[2 * eh + 1] = v.z; ai[2 * eh + 1] = v.w;
    }
    // R_L(4..9) lane, R_L(10..12) local (R_L(0..3) were done in Q(L-1))
    #pragma unroll
    for (int q = 4; q <= 9; ++q)
      rot_lane(ar, ai, gl + q * 8, 1 << (q - 4), (tid >> (q - 4)) & 1);
    rot_local<1>(ar, ai, gl + 80);
    rot_local<2>(ar, ai, gl + 88);
    rot_local<3>(ar, ai, gl + 96);
  }

  // ring prefix: g in [gstart, 11-L], targets t=g+r in [4,12]
  constexpr int gstart = (L == 0) ? 3 : (L == 1) ? 2 : (L == 2) ? 1 : 0;
  static_for<(11 - L) - gstart + 1>([&](auto gc) {
    constexpr int g = gstart + gc.value;
    constexpr int t = g + r;
    if constexpr (t <= 9) cnot_lane<10, g>(ar, ai, 1 << (t - 4), ibase);
    else                  cnot_local<t - 9, 10, g>(ar, ai, ibase);
  });

  #pragma unroll
  for (int eh = 0; eh < 8; ++eh)
    *reinterpret_cast<float4*>(base + (eh << 10)) =
        make_float4(ar[2 * eh], ai[2 * eh], ar[2 * eh + 1], ai[2 * eh + 1]);
}

// ---------------- Sweep Q ----------------
template <int L>
__global__ void __launch_bounds__(NTH) sweepQ(float2* __restrict__ st,
                                              const float* __restrict__ gm,
                                              float* __restrict__ part) {
  const int tid = threadIdx.x;
  const int s  = blockIdx.x >> 3;
  const int fb = blockIdx.x & 7;
  // amp bits: 0..3 local | 4..6 = tid0-2 | 13..15 = tid3-5 | 10..12 = tid6-8 | 7..9 = fb
  const int ibase = ((tid & 7) << 4) | (((tid >> 3) & 7) << 13) |
                    (((tid >> 6) & 7) << 10) | (fb << 7);
  float2* __restrict__ base = st + (s << 16) + ibase;
  constexpr int r = L + 1;
  const float* __restrict__ gl = gm + L * 128;
  v16f ar, ai;
  #pragma unroll
  for (int eh = 0; eh < 8; ++eh) {
    const float4 v = *reinterpret_cast<const float4*>(base + 2 * eh);
    ar[2 * eh] = v.x; ai[2 * eh] = v.y; ar[2 * eh + 1] = v.z; ai[2 * eh + 1] = v.w;
  }
  if constexpr (L > 0) {  // R_L(13..15); layer 0's were folded into init
    rot_lane(ar, ai, gl + 104, 8,  (tid >> 3) & 1);
    rot_lane(ar, ai, gl + 112, 16, (tid >> 4) & 1);
    rot_lane(ar, ai, gl + 120, 32, (tid >> 5) & 1);
  }
  // ring suffix: g in [12-L, 15]; targets in {13,14,15} U {0..r-1}; controls >= 7
  static_for<L + 4>([&](auto gc) {
    constexpr int g = 12 - L + gc.value;
    constexpr int t = (g + r) & 15;
    if constexpr (t >= 13)     cnot_lane<1, g>(ar, ai, 1 << (t - 10), ibase);
    else if constexpr (t >= 4) cnot_lane<1, g>(ar, ai, 1 << (t - 4), ibase);
    else                       cnot_local<t, 1, g>(ar, ai, ibase);
  });

  if constexpr (L < 5) {
    // head of layer L+1: R_{L+1}(0..3) local, + early in-tile CNOTs
    const float* __restrict__ gn = gm + (L + 1) * 128;
    rot_local<0>(ar, ai, gn);
    rot_local<1>(ar, ai, gn + 8);
    rot_local<2>(ar, ai, gn + 16);
    rot_local<3>(ar, ai, gn + 24);
    if constexpr (L == 0) {
      cnot_local<2, 1, 0>(ar, ai, ibase);  // C_1(0,2)
      cnot_local<3, 1, 1>(ar, ai, ibase);  // C_1(1,3)
    }
    if constexpr (L == 1) {
      cnot_local<3, 1, 0>(ar, ai, ibase);  // C_2(0,3)
    }
    #pragma unroll
    for (int eh = 0; eh < 8; ++eh)
      *reinterpret_cast<float4*>(base + 2 * eh) =
          make_float4(ar[2 * eh], ai[2 * eh], ar[2 * eh + 1], ai[2 * eh + 1]);
  } else {
    // fused measurement: per-block partial <Z_q> sums (no state store)
    __shared__ float red[8][16];
    float tot = 0.f, sl0 = 0.f, sl1 = 0.f, sl2 = 0.f, sl3 = 0.f;
    static_for<16>([&](auto ec) {
      constexpr int e = ec.value;
      const float p = ar[e] * ar[e] + ai[e] * ai[e];
      tot += p;
      if constexpr (e & 1) sl0 -= p; else sl0 += p;
      if constexpr (e & 2) sl1 -= p; else sl1 += p;
      if constexpr (e & 4) sl2 -= p; else sl2 += p;
      if constexpr (e & 8) sl3 -= p; else sl3 += p;
    });
    const float sl[4] = {sl0, sl1, sl2, sl3};
    const int wv = tid >> 6;
    static_for<16>([&](auto qc) {
      constexpr int q = qc.value;
      float v;
      if constexpr (q < 4) v = sl[q];
      else v = ((ibase >> q) & 1) ? -tot : tot;
      v += __shfl_xor(v, 1);  v += __shfl_xor(v, 2);  v += __shfl_xor(v, 4);
      v += __shfl_xor(v, 8);  v += __shfl_xor(v, 16); v += __shfl_xor(v, 32);
      if ((tid & 63) == 0) red[wv][q] = v;
    });
    __syncthreads();
    if (tid < 16) {
      float a = 0.f;
      #pragma unroll
      for (int w8 = 0; w8 < 8; ++w8) a += red[w8][tid];
      part[blockIdx.x * 16 + tid] = a;
    }
  }
}

// ---------------- final reduce: 8 block-partials -> out ----------------
__global__ void __launch_bounds__(NTH) reduceK(const float* __restrict__ part,
                                               float* __restrict__ out) {
  const int j = blockIdx.x * NTH + threadIdx.x;  // j = s*16 + q, j < 8192
  const int s = j >> 4, q = j & 15;
  float a = 0.f;
  #pragma unroll
  for (int fb = 0; fb < 8; ++fb) a += part[(s << 7) + fb * 16 + q];
  out[j] = a;
}

extern "C" void kernel_launch(void* const* d_in, const int* in_sizes, int n_in,
                              void* d_out, int out_size, void* d_ws, size_t ws_size,
                              hipStream_t stream) {
  (void)in_sizes; (void)n_in; (void)out_size;
  const float* x = (const float*)d_in[0];
  const float* w = (const float*)d_in[1];
  float* out = (float*)d_out;
  float* gm   = (float*)d_ws;                          // 768 floats
  float* part = (float*)((char*)d_ws + 4096);          // 512*8*16 floats = 256 KB
  float2* st  = (float2*)((char*)d_ws + 524288);       // state, chunked to fit ws

  const size_t avail = ws_size > 524288 ? ws_size - 524288 : 0;
  long long chunk = (long long)(avail / 524288);       // 512 KB per sample
  if (chunk > 512) chunk = 512;
  if (chunk < 1) chunk = 1;

  qsim_prep<<<dim3(1), dim3(128), 0, stream>>>(w, gm);
  for (int s0 = 0; s0 < 512; s0 += (int)chunk) {
    const int ns = (512 - s0) < (int)chunk ? (512 - s0) : (int)chunk;
    const dim3 g(ns * 8), b(NTH);
    const float* xs = x + s0 * 16;
    float* pp = part + (size_t)s0 * 128;
    sweepP<0><<<g, b, 0, stream>>>(st, xs, gm);
    sweepQ<0><<<g, b, 0, stream>>>(st, gm, pp);
    sweepP<1><<<g, b, 0, stream>>>(st, xs, gm);
    sweepQ<1><<<g, b, 0, stream>>>(st, gm, pp);
    sweepP<2><<<g, b, 0, stream>>>(st, xs, gm);
    sweepQ<2><<<g, b, 0, stream>>>(st, gm, pp);
    sweepP<3><<<g, b, 0, stream>>>(st, xs, gm);
    sweepQ<3><<<g, b, 0, stream>>>(st, gm, pp);
    sweepP<4><<<g, b, 0, stream>>>(st, xs, gm);
    sweepQ<4><<<g, b, 0, stream>>>(st, gm, pp);
    sweepP<5><<<g, b, 0, stream>>>(st, xs, gm);
    sweepQ<5><<<g, b, 0, stream>>>(st, gm, pp);
  }
  reduceK<<<dim3(16), dim3(NTH), 0, stream>>>(part, out);
}

// Round 2
// 1619.523 us; speedup vs baseline: 2.1115x; 1.3321x over previous
//
#include <hip/hip_runtime.h>

// 16-qubit statevector, 512 samples, 6 StronglyEntanglingLayers, qubit q <-> bit q.
// Round 9: coalesced PHYSICAL state layout + L3-resident batch chunks.
// Gate schedule (unchanged from round 8, r = l+1):
//   P(l): tile amp bits 0-12, fixed 13-15; local={0,10,11,12}, lane={4..9}(tid0-5),
//         wave={1,2,3}(tid6-8). R_l(4..12) + ring prefix (targets in [4,12]).
//   Q(l): tile bits 0-6,10-15, fixed 7-9; local={0,1,2,3}, lane={4,5,6}(tid0-2)
//         +{13,14,15}(tid3-5), wave={10,11,12}(tid6-8). R_l(13..15), ring suffix,
//         head of layer l+1 (R_{l+1}(0..3) + early CNOTs); Q(5) fuses measurement.
// NEW: state is stored under a fixed bit permutation pi: amp->phys
//   p0=amp0 | p1..6=amp4..9 | p7..9=amp1..3 | p10..12=amp10..12 | p13..15=amp13..15
// so a P wave instruction covers 1024B contiguous (was 64x16B @128B stride, 2.5x
// write amplification per rocprof), and Q keeps 128B-dense segments. Gate logic
// still runs in amp space (ibase/EIdx unchanged). Chunk capped at 256 samples
// (128 MB) so the whole 12-sweep chunk cycles inside the 256 MB Infinity Cache.

#define NTH 512
typedef float v16f __attribute__((ext_vector_type(16)));

template <int I> struct IC { static constexpr int value = I; };
template <int N, int I = 0, typename F>
__device__ __forceinline__ void static_for(F&& f) {
  if constexpr (I < N) { f(IC<I>{}); static_for<N, I + 1>(f); }
}

// element e -> amp-space local bits. SH=1: identity (Q: amps 0-3). SH=10: amp0 + amps10-12 (P).
template <int SH, int E> struct EIdx { static constexpr int v = (E & 1) | ((E >> 1) << SH); };

// ---------------- gate helpers on 16 reg amps ----------------

template <int LB>  // Rot on local e-bit LB
__device__ __forceinline__ void rot_local(v16f& ar, v16f& ai, const float* __restrict__ u) {
  const float u00r = u[0], u00i = u[1], u01r = u[2], u01i = u[3];
  const float u10r = u[4], u10i = u[5], u11r = u[6], u11i = u[7];
  static_for<8>([&](auto hc) {
    constexpr int h = hc.value;
    constexpr int e0 = ((h >> LB) << (LB + 1)) | (h & ((1 << LB) - 1));
    constexpr int e1 = e0 | (1 << LB);
    const float axr = ar[e0], axi = ai[e0], bxr = ar[e1], bxi = ai[e1];
    ar[e0] = u00r * axr - u00i * axi + u01r * bxr - u01i * bxi;
    ai[e0] = u00r * axi + u00i * axr + u01r * bxi + u01i * bxr;
    ar[e1] = u10r * axr - u10i * axi + u11r * bxr - u11i * bxi;
    ai[e1] = u10r * axi + u10i * axr + u11r * bxi + u11i * bxr;
  });
}

// Rot on a lane bit: shfl mask m, bit = this lane's bit value
__device__ __forceinline__ void rot_lane(v16f& ar, v16f& ai, const float* __restrict__ u,
                                         const int m, const int bit) {
  const float car = bit ? u[6] : u[0], cai = bit ? u[7] : u[1];
  const float cbr = bit ? u[4] : u[2], cbi = bit ? u[5] : u[3];
  static_for<16>([&](auto ec) {
    constexpr int e = ec.value;
    const float orr = ar[e], oii = ai[e];
    const float pr = __shfl_xor(orr, m);
    const float pi = __shfl_xor(oii, m);
    ar[e] = car * orr - cai * oii + cbr * pr - cbi * pi;
    ai[e] = car * oii + cai * orr + cbr * pi + cbi * pr;
  });
}

// CNOT, lane-bit target (shfl mask m), control amp-bit C (compile-time).
template <int SH, int C>
__device__ __forceinline__ void cnot_lane(v16f& ar, v16f& ai, const int m, const int ibase) {
  if constexpr ((EIdx<SH, 15>::v >> C) & 1) {
    static_for<16>([&](auto ec) {
      constexpr int e = ec.value;
      if constexpr ((EIdx<SH, e>::v >> C) & 1) {
        ar[e] = __shfl_xor(ar[e], m);
        ai[e] = __shfl_xor(ai[e], m);
      }
    });
  } else {
    if ((ibase >> C) & 1) {
      static_for<16>([&](auto ec) {
        constexpr int e = ec.value;
        ar[e] = __shfl_xor(ar[e], m);
        ai[e] = __shfl_xor(ai[e], m);
      });
    }
  }
}

// CNOT, local e-bit target TB, control amp-bit C (compile-time, C != target bit).
template <int TB, int SH, int C>
__device__ __forceinline__ void cnot_local(v16f& ar, v16f& ai, const int ibase) {
  static_for<8>([&](auto hc) {
    constexpr int h = hc.value;
    constexpr int e0 = ((h >> TB) << (TB + 1)) | (h & ((1 << TB) - 1));
    constexpr int e1 = e0 | (1 << TB);
    if constexpr ((EIdx<SH, 15>::v >> C) & 1) {
      if constexpr ((EIdx<SH, e0>::v >> C) & 1) {  // static: pure register swap
        const float tr = ar[e0], ti = ai[e0];
        ar[e0] = ar[e1]; ai[e0] = ai[e1];
        ar[e1] = tr;     ai[e1] = ti;
      }
    } else {
      const int take = (ibase >> C) & 1;
      const float axr = ar[e0], axi = ai[e0], bxr = ar[e1], bxi = ai[e1];
      ar[e0] = take ? bxr : axr; ai[e0] = take ? bxi : axi;
      ar[e1] = take ? axr : bxr; ai[e1] = take ? axi : bxi;
    }
  });
}

// ---------------- prep: 96 Rot matrices ----------------
__global__ void qsim_prep(const float* __restrict__ w, float* __restrict__ gm) {
  const int i = threadIdx.x;
  if (i < 96) {
    const float phi = w[i * 3 + 0];
    const float th  = w[i * 3 + 1];
    const float om  = w[i * 3 + 2];
    float st, ct; sincosf(0.5f * th, &st, &ct);
    float sa, ca; sincosf(0.5f * (phi + om), &sa, &ca);
    float sb, cb; sincosf(0.5f * (phi - om), &sb, &cb);
    float* u = gm + i * 8;
    u[0] =  ct * ca; u[1] = -ct * sa;   // m00
    u[2] = -st * cb; u[3] = -st * sb;   // m01
    u[4] =  st * cb; u[5] = -st * sb;   // m10
    u[6] =  ct * ca; u[7] =  ct * sa;   // m11
  }
}

// ---------------- Sweep P ----------------
template <int L>
__global__ void __launch_bounds__(NTH) sweepP(float2* __restrict__ st,
                                              const float* __restrict__ x,
                                              const float* __restrict__ gm) {
  const int tid = threadIdx.x;
  const int s  = blockIdx.x >> 3;
  const int fb = blockIdx.x & 7;
  // amp-space base (gate logic): bits 0,10,11,12 local | 4..9=tid0-5 | 1,2,3=tid6-8 | 13..15=fb
  const int ibase = (fb << 13) | ((tid & 63) << 4) | ((tid >> 6) << 1);
  // phys-space base (memory): amp0->p0, amp4..9->p1..6, amp1..3->p7..9, amp10..12->p10..12
  const int pbase = (fb << 13) | ((tid & 63) << 1) | ((tid >> 6) << 7);
  float2* __restrict__ base = st + (s << 16) + pbase;
  constexpr int r = L + 1;
  const float* __restrict__ gl = gm + L * 128;
  v16f ar, ai;

  if constexpr (L == 0) {
    // init: product of v_q = Rot_0(q) * RX(x_q)|0>, chain (0,1),(1,2),(2,3) folded.
    __shared__ float iv[16][4];
    if (tid < 16) {
      const float* u = gm + tid * 8;
      float sx, cx; sincosf(0.5f * x[s * 16 + tid], &sx, &cx);
      iv[tid][0] = u[0] * cx + u[3] * sx;   // v0r
      iv[tid][1] = u[1] * cx - u[2] * sx;   // v0i
      iv[tid][2] = u[4] * cx + u[7] * sx;   // v1r
      iv[tid][3] = u[5] * cx - u[6] * sx;   // v1i
    }
    __syncthreads();
    float Tr = 1.f, Ti = 0.f;
    #pragma unroll
    for (int b = 4; b <= 9; ++b) {
      const int bit = (ibase >> b) & 1;
      const float fr = iv[b][2 * bit], fi = iv[b][2 * bit + 1];
      const float nr = Tr * fr - Ti * fi; Ti = Tr * fi + Ti * fr; Tr = nr;
    }
    #pragma unroll
    for (int b = 13; b <= 15; ++b) {
      const int bit = (ibase >> b) & 1;
      const float fr = iv[b][2 * bit], fi = iv[b][2 * bit + 1];
      const float nr = Tr * fr - Ti * fi; Ti = Tr * fi + Ti * fr; Tr = nr;
    }
    const int b1 = (ibase >> 1) & 1, b2 = (ibase >> 2) & 1, b3 = (ibase >> 3) & 1;
    float Wr[2], Wi[2];
    #pragma unroll
    for (int b0 = 0; b0 < 2; ++b0) {
      const int c1 = b0 ^ b1, c2 = b1 ^ b2, c3 = b2 ^ b3;
      float wr = iv[0][2 * b0], wi = iv[0][2 * b0 + 1];
      { const float fr = iv[1][2 * c1], fi = iv[1][2 * c1 + 1];
        const float nr = wr * fr - wi * fi; wi = wr * fi + wi * fr; wr = nr; }
      { const float fr = iv[2][2 * c2], fi = iv[2][2 * c2 + 1];
        const float nr = wr * fr - wi * fi; wi = wr * fi + wi * fr; wr = nr; }
      { const float fr = iv[3][2 * c3], fi = iv[3][2 * c3 + 1];
        const float nr = wr * fr - wi * fi; wi = wr * fi + wi * fr; wr = nr; }
      Wr[b0] = wr * Tr - wi * Ti; Wi[b0] = wr * Ti + wi * Tr;
    }
    ar[0] = Wr[0]; ai[0] = Wi[0]; ar[1] = Wr[1]; ai[1] = Wi[1];
    static_for<3>([&](auto bc) {
      constexpr int bI = bc.value;
      const int q = 10 + bI;
      const float v0r = iv[q][0], v0i = iv[q][1], v1r = iv[q][2], v1i = iv[q][3];
      static_for<(1 << (bI + 1))>([&](auto kc) {
        constexpr int k = kc.value;
        constexpr int k1 = k | (1 << (bI + 1));
        const float kr = ar[k], ki = ai[k];
        ar[k1] = kr * v1r - ki * v1i; ai[k1] = kr * v1i + ki * v1r;
        ar[k]  = kr * v0r - ki * v0i; ai[k]  = kr * v0i + ki * v0r;
      });
    });
  } else {
    #pragma unroll
    for (int eh = 0; eh < 8; ++eh) {
      const float4 v = *reinterpret_cast<const float4*>(base + (eh << 10));
      ar[2 * eh] = v.x; ai[2 * eh] = v.y; ar[2 * eh + 1] = v.z; ai[2 * eh + 1] = v.w;
    }
    #pragma unroll
    for (int q = 4; q <= 9; ++q)
      rot_lane(ar, ai, gl + q * 8, 1 << (q - 4), (tid >> (q - 4)) & 1);
    rot_local<1>(ar, ai, gl + 80);
    rot_local<2>(ar, ai, gl + 88);
    rot_local<3>(ar, ai, gl + 96);
  }

  // ring prefix: g in [gstart, 11-L], targets t=g+r in [4,12]
  constexpr int gstart = (L == 0) ? 3 : (L == 1) ? 2 : (L == 2) ? 1 : 0;
  static_for<(11 - L) - gstart + 1>([&](auto gc) {
    constexpr int g = gstart + gc.value;
    constexpr int t = g + r;
    if constexpr (t <= 9) cnot_lane<10, g>(ar, ai, 1 << (t - 4), ibase);
    else                  cnot_local<t - 9, 10, g>(ar, ai, ibase);
  });

  #pragma unroll
  for (int eh = 0; eh < 8; ++eh)
    *reinterpret_cast<float4*>(base + (eh << 10)) =
        make_float4(ar[2 * eh], ai[2 * eh], ar[2 * eh + 1], ai[2 * eh + 1]);
}

// ---------------- Sweep Q ----------------
template <int L>
__global__ void __launch_bounds__(NTH) sweepQ(float2* __restrict__ st,
                                              const float* __restrict__ gm,
                                              float* __restrict__ part) {
  const int tid = threadIdx.x;
  const int s  = blockIdx.x >> 3;
  const int fb = blockIdx.x & 7;
  // amp-space base: 0..3 local | 4..6=tid0-2 | 13..15=tid3-5 | 10..12=tid6-8 | 7..9=fb
  const int ibase = ((tid & 7) << 4) | (((tid >> 3) & 7) << 13) |
                    (((tid >> 6) & 7) << 10) | (fb << 7);
  // phys-space base: amp4..6->p1..3, amp7..9->p4..6, amp1..3->p7..9 (locals),
  //                  amp10..12->p10..12, amp13..15->p13..15
  const int pbase = ((tid & 7) << 1) | (fb << 4) |
                    (((tid >> 6) & 7) << 10) | (((tid >> 3) & 7) << 13);
  float2* __restrict__ base = st + (s << 16) + pbase;
  constexpr int r = L + 1;
  const float* __restrict__ gl = gm + L * 128;
  v16f ar, ai;
  #pragma unroll
  for (int eh = 0; eh < 8; ++eh) {
    const float4 v = *reinterpret_cast<const float4*>(base + (eh << 7));
    ar[2 * eh] = v.x; ai[2 * eh] = v.y; ar[2 * eh + 1] = v.z; ai[2 * eh + 1] = v.w;
  }
  if constexpr (L > 0) {  // R_L(13..15); layer 0's were folded into init
    rot_lane(ar, ai, gl + 104, 8,  (tid >> 3) & 1);
    rot_lane(ar, ai, gl + 112, 16, (tid >> 4) & 1);
    rot_lane(ar, ai, gl + 120, 32, (tid >> 5) & 1);
  }
  // ring suffix: g in [12-L, 15]; targets in {13,14,15} U {0..r-1}; controls >= 7
  static_for<L + 4>([&](auto gc) {
    constexpr int g = 12 - L + gc.value;
    constexpr int t = (g + r) & 15;
    if constexpr (t >= 13)     cnot_lane<1, g>(ar, ai, 1 << (t - 10), ibase);
    else if constexpr (t >= 4) cnot_lane<1, g>(ar, ai, 1 << (t - 4), ibase);
    else                       cnot_local<t, 1, g>(ar, ai, ibase);
  });

  if constexpr (L < 5) {
    // head of layer L+1: R_{L+1}(0..3) local, + early in-tile CNOTs
    const float* __restrict__ gn = gm + (L + 1) * 128;
    rot_local<0>(ar, ai, gn);
    rot_local<1>(ar, ai, gn + 8);
    rot_local<2>(ar, ai, gn + 16);
    rot_local<3>(ar, ai, gn + 24);
    if constexpr (L == 0) {
      cnot_local<2, 1, 0>(ar, ai, ibase);  // C_1(0,2)
      cnot_local<3, 1, 1>(ar, ai, ibase);  // C_1(1,3)
    }
    if constexpr (L == 1) {
      cnot_local<3, 1, 0>(ar, ai, ibase);  // C_2(0,3)
    }
    #pragma unroll
    for (int eh = 0; eh < 8; ++eh)
      *reinterpret_cast<float4*>(base + (eh << 7)) =
          make_float4(ar[2 * eh], ai[2 * eh], ar[2 * eh + 1], ai[2 * eh + 1]);
  } else {
    // fused measurement: per-block partial <Z_q> sums (no state store)
    __shared__ float red[8][16];
    float tot = 0.f, sl0 = 0.f, sl1 = 0.f, sl2 = 0.f, sl3 = 0.f;
    static_for<16>([&](auto ec) {
      constexpr int e = ec.value;
      const float p = ar[e] * ar[e] + ai[e] * ai[e];
      tot += p;
      if constexpr (e & 1) sl0 -= p; else sl0 += p;
      if constexpr (e & 2) sl1 -= p; else sl1 += p;
      if constexpr (e & 4) sl2 -= p; else sl2 += p;
      if constexpr (e & 8) sl3 -= p; else sl3 += p;
    });
    const float sl[4] = {sl0, sl1, sl2, sl3};
    const int wv = tid >> 6;
    static_for<16>([&](auto qc) {
      constexpr int q = qc.value;
      float v;
      if constexpr (q < 4) v = sl[q];
      else v = ((ibase >> q) & 1) ? -tot : tot;
      v += __shfl_xor(v, 1);  v += __shfl_xor(v, 2);  v += __shfl_xor(v, 4);
      v += __shfl_xor(v, 8);  v += __shfl_xor(v, 16); v += __shfl_xor(v, 32);
      if ((tid & 63) == 0) red[wv][q] = v;
    });
    __syncthreads();
    if (tid < 16) {
      float a = 0.f;
      #pragma unroll
      for (int w8 = 0; w8 < 8; ++w8) a += red[w8][tid];
      part[blockIdx.x * 16 + tid] = a;
    }
  }
}

// ---------------- final reduce: 8 block-partials -> out ----------------
__global__ void __launch_bounds__(NTH) reduceK(const float* __restrict__ part,
                                               float* __restrict__ out) {
  const int j = blockIdx.x * NTH + threadIdx.x;  // j = s*16 + q, j < 8192
  const int s = j >> 4, q = j & 15;
  float a = 0.f;
  #pragma unroll
  for (int fb = 0; fb < 8; ++fb) a += part[(s << 7) + fb * 16 + q];
  out[j] = a;
}

extern "C" void kernel_launch(void* const* d_in, const int* in_sizes, int n_in,
                              void* d_out, int out_size, void* d_ws, size_t ws_size,
                              hipStream_t stream) {
  (void)in_sizes; (void)n_in; (void)out_size;
  const float* x = (const float*)d_in[0];
  const float* w = (const float*)d_in[1];
  float* out = (float*)d_out;
  float* gm   = (float*)d_ws;                          // 768 floats
  float* part = (float*)((char*)d_ws + 4096);          // 512*8*16 floats = 256 KB
  float2* st  = (float2*)((char*)d_ws + 524288);       // state, chunked to fit ws

  const size_t avail = ws_size > 524288 ? ws_size - 524288 : 0;
  long long chunk = (long long)(avail / 524288);       // 512 KB per sample
  if (chunk > 256) chunk = 256;                        // 128 MB: L3-resident chunk
  if (chunk < 1) chunk = 1;

  qsim_prep<<<dim3(1), dim3(128), 0, stream>>>(w, gm);
  for (int s0 = 0; s0 < 512; s0 += (int)chunk) {
    const int ns = (512 - s0) < (int)chunk ? (512 - s0) : (int)chunk;
    const dim3 g(ns * 8), b(NTH);
    const float* xs = x + s0 * 16;
    float* pp = part + (size_t)s0 * 128;
    sweepP<0><<<g, b, 0, stream>>>(st, xs, gm);
    sweepQ<0><<<g, b, 0, stream>>>(st, gm, pp);
    sweepP<1><<<g, b, 0, stream>>>(st, xs, gm);
    sweepQ<1><<<g, b, 0, stream>>>(st, gm, pp);
    sweepP<2><<<g, b, 0, stream>>>(st, xs, gm);
    sweepQ<2><<<g, b, 0, stream>>>(st, gm, pp);
    sweepP<3><<<g, b, 0, stream>>>(st, xs, gm);
    sweepQ<3><<<g, b, 0, stream>>>(st, gm, pp);
    sweepP<4><<<g, b, 0, stream>>>(st, xs, gm);
    sweepQ<4><<<g, b, 0, stream>>>(st, gm, pp);
    sweepP<5><<<g, b, 0, stream>>>(st, xs, gm);
    sweepQ<5><<<g, b, 0, stream>>>(st, gm, pp);
  }
  reduceK<<<dim3(16), dim3(NTH), 0, stream>>>(part, out);
}

// Round 3
// 1579.229 us; speedup vs baseline: 2.1654x; 1.0255x over previous
//
#include <hip/hip_runtime.h>

// 16-qubit statevector, 512 samples, 6 StronglyEntanglingLayers, qubit q <-> bit q.
// Round 10: SYMMETRIC memory morphology. Evidence: round-9 sweepQ streams at
// ~6.4 TB/s while sweepP (even the pure-write P<0>) crawls at ~2 TB/s with
// spurious 64MB fetches -> P's access morphology is the problem. New split makes
// both kernels use Q's proven pattern (8 dense 128B lines / wave instr,
// per-thread footprint <= 1KB).
//
// Accessible = {locals} U {lanes}; CNOT controls are ALWAYS readable (index bits).
//   P'(l): locals a{0,1,2,3}, lanes a{4..9}; waves a{10,11,12}, fixed a{13,14,15}.
//          Does: deferred wrapped CNOT_{l-1} (controls>=10, targets 0..l-1),
//          R_l(0..9), ring g=0..9-r (targets r..9).
//   Q'(l): locals a{0,10,11,12}, lanes a{4,5,6}+{13,14,15}; waves a{7,8,9},
//          fixed a{1,2,3}. Does: R_l(10..15), ring g=10-r..15-r (targets 10..15).
//          Wrapped gates g=16-r..15 defer to P'(l+1); layer-5's 6 wrapped gates
//          + measurement go to finalK (read-only pass, P' tiling).
//   P'(0): init = product of v_q = Rot_0(q)*RX(x_q)|0> for ALL q (rots folded),
//          then ring g=0..8.
// Physical bit permutation (fixed): p0=a0 | p1-3=a4-6 | p4-6=a1-3 | p7-9=a10-12
//   | p10-12=a13-15 | p13-15=a7-9.  Both kernels: lanes tid0-2 -> p1-3 (128B
//   contiguous), per-thread local loads at 128B (P') / 1KB (Q') stride.
// Chunk = 256 samples (128 MB) for L3 residency.

#define NTH 512
typedef float v16f __attribute__((ext_vector_type(16)));

template <int I> struct IC { static constexpr int value = I; };
template <int N, int I = 0, typename F>
__device__ __forceinline__ void static_for(F&& f) {
  if constexpr (I < N) { f(IC<I>{}); static_for<N, I + 1>(f); }
}

// element e -> amp-space local bits. SH=1: e = amp0-3 (P'). SH=10: amp0 + amp10-12 (Q').
template <int SH, int E> struct EIdx { static constexpr int v = (E & 1) | ((E >> 1) << SH); };

// ---------------- gate helpers on 16 reg amps ----------------

template <int LB>  // Rot on local e-bit LB
__device__ __forceinline__ void rot_local(v16f& ar, v16f& ai, const float* __restrict__ u) {
  const float u00r = u[0], u00i = u[1], u01r = u[2], u01i = u[3];
  const float u10r = u[4], u10i = u[5], u11r = u[6], u11i = u[7];
  static_for<8>([&](auto hc) {
    constexpr int h = hc.value;
    constexpr int e0 = ((h >> LB) << (LB + 1)) | (h & ((1 << LB) - 1));
    constexpr int e1 = e0 | (1 << LB);
    const float axr = ar[e0], axi = ai[e0], bxr = ar[e1], bxi = ai[e1];
    ar[e0] = u00r * axr - u00i * axi + u01r * bxr - u01i * bxi;
    ai[e0] = u00r * axi + u00i * axr + u01r * bxi + u01i * bxr;
    ar[e1] = u10r * axr - u10i * axi + u11r * bxr - u11i * bxi;
    ai[e1] = u10r * axi + u10i * axr + u11r * bxi + u11i * bxr;
  });
}

// Rot on a lane bit: shfl mask m, bit = this lane's bit value
__device__ __forceinline__ void rot_lane(v16f& ar, v16f& ai, const float* __restrict__ u,
                                         const int m, const int bit) {
  const float car = bit ? u[6] : u[0], cai = bit ? u[7] : u[1];
  const float cbr = bit ? u[4] : u[2], cbi = bit ? u[5] : u[3];
  static_for<16>([&](auto ec) {
    constexpr int e = ec.value;
    const float orr = ar[e], oii = ai[e];
    const float pr = __shfl_xor(orr, m);
    const float pi = __shfl_xor(oii, m);
    ar[e] = car * orr - cai * oii + cbr * pr - cbi * pi;
    ai[e] = car * oii + cai * orr + cbr * pi + cbi * pr;
  });
}

// CNOT, lane-bit target (shfl mask m), control amp-bit C (compile-time).
// C local -> static per-element participation; else thread-uniform-per-pair branch
// (partner lanes differ only in the target bit, so branch is shfl-safe).
template <int SH, int C>
__device__ __forceinline__ void cnot_lane(v16f& ar, v16f& ai, const int m, const int ibase) {
  if constexpr ((EIdx<SH, 15>::v >> C) & 1) {
    static_for<16>([&](auto ec) {
      constexpr int e = ec.value;
      if constexpr ((EIdx<SH, e>::v >> C) & 1) {
        ar[e] = __shfl_xor(ar[e], m);
        ai[e] = __shfl_xor(ai[e], m);
      }
    });
  } else {
    if ((ibase >> C) & 1) {
      static_for<16>([&](auto ec) {
        constexpr int e = ec.value;
        ar[e] = __shfl_xor(ar[e], m);
        ai[e] = __shfl_xor(ai[e], m);
      });
    }
  }
}

// CNOT, local e-bit target TB, control amp-bit C (compile-time, C != target bit).
template <int TB, int SH, int C>
__device__ __forceinline__ void cnot_local(v16f& ar, v16f& ai, const int ibase) {
  static_for<8>([&](auto hc) {
    constexpr int h = hc.value;
    constexpr int e0 = ((h >> TB) << (TB + 1)) | (h & ((1 << TB) - 1));
    constexpr int e1 = e0 | (1 << TB);
    if constexpr ((EIdx<SH, 15>::v >> C) & 1) {
      if constexpr ((EIdx<SH, e0>::v >> C) & 1) {  // static: pure register swap
        const float tr = ar[e0], ti = ai[e0];
        ar[e0] = ar[e1]; ai[e0] = ai[e1];
        ar[e1] = tr;     ai[e1] = ti;
      }
    } else {
      const int take = (ibase >> C) & 1;
      const float axr = ar[e0], axi = ai[e0], bxr = ar[e1], bxi = ai[e1];
      ar[e0] = take ? bxr : axr; ai[e0] = take ? bxi : axi;
      ar[e1] = take ? axr : bxr; ai[e1] = take ? axi : bxi;
    }
  });
}

// ---------------- prep: 96 Rot matrices ----------------
__global__ void qsim_prep(const float* __restrict__ w, float* __restrict__ gm) {
  const int i = threadIdx.x;
  if (i < 96) {
    const float phi = w[i * 3 + 0];
    const float th  = w[i * 3 + 1];
    const float om  = w[i * 3 + 2];
    float st, ct; sincosf(0.5f * th, &st, &ct);
    float sa, ca; sincosf(0.5f * (phi + om), &sa, &ca);
    float sb, cb; sincosf(0.5f * (phi - om), &sb, &cb);
    float* u = gm + i * 8;
    u[0] =  ct * ca; u[1] = -ct * sa;   // m00
    u[2] = -st * cb; u[3] = -st * sb;   // m01
    u[4] =  st * cb; u[5] = -st * sb;   // m10
    u[6] =  ct * ca; u[7] =  ct * sa;   // m11
  }
}

// ---------------- Sweep P' : accessible {0..9} ----------------
template <int L>
__global__ void __launch_bounds__(NTH) sweepP(float2* __restrict__ st,
                                              const float* __restrict__ x,
                                              const float* __restrict__ gm) {
  const int tid = threadIdx.x;
  const int s  = blockIdx.x >> 3;
  const int fb = blockIdx.x & 7;
  // amp: e=a0-3 | a4-6=tid0-2 | a7-9=tid3-5 | a10-12=tid6-8 | a13-15=fb
  const int ibase = ((tid & 7) << 4) | (((tid >> 3) & 7) << 7) |
                    (((tid >> 6) & 7) << 10) | (fb << 13);
  // phys: a4-6->p1-3, a1-3->p4-6(eh), a10-12->p7-9, a13-15->p10-12, a7-9->p13-15
  const int pbase = ((tid & 7) << 1) | (((tid >> 6) & 7) << 7) | (fb << 10) |
                    (((tid >> 3) & 7) << 13);
  float2* __restrict__ base = st + (s << 16) + pbase;
  constexpr int r = L + 1;
  const float* __restrict__ gl = gm + L * 128;
  v16f ar, ai;

  if constexpr (L == 0) {
    // init: |psi> = prod_q v_q, v_q = Rot_0(q)*RX(x_q)|0>  (ALL 16 rots folded)
    __shared__ float iv[16][4];
    if (tid < 16) {
      const float* u = gm + tid * 8;
      float sx, cx; sincosf(0.5f * x[s * 16 + tid], &sx, &cx);
      iv[tid][0] = u[0] * cx + u[3] * sx;   // v0r
      iv[tid][1] = u[1] * cx - u[2] * sx;   // v0i
      iv[tid][2] = u[4] * cx + u[7] * sx;   // v1r
      iv[tid][3] = u[5] * cx - u[6] * sx;   // v1i
    }
    __syncthreads();
    float Tr = 1.f, Ti = 0.f;
    #pragma unroll
    for (int b = 4; b <= 15; ++b) {
      const int bit = (ibase >> b) & 1;
      const float fr = iv[b][2 * bit], fi = iv[b][2 * bit + 1];
      const float nr = Tr * fr - Ti * fi; Ti = Tr * fi + Ti * fr; Tr = nr;
    }
    ar[0] = Tr; ai[0] = Ti;
    // expand local e-bits 0..3 = qubits 0..3
    static_for<4>([&](auto bc) {
      constexpr int bI = bc.value;
      const float v0r = iv[bI][0], v0i = iv[bI][1], v1r = iv[bI][2], v1i = iv[bI][3];
      static_for<(1 << bI)>([&](auto kc) {
        constexpr int k = kc.value;
        constexpr int k1 = k | (1 << bI);
        const float kr = ar[k], ki = ai[k];
        ar[k1] = kr * v1r - ki * v1i; ai[k1] = kr * v1i + ki * v1r;
        ar[k]  = kr * v0r - ki * v0i; ai[k]  = kr * v0i + ki * v0r;
      });
    });
  } else {
    #pragma unroll
    for (int eh = 0; eh < 8; ++eh) {
      const float4 v = *reinterpret_cast<const float4*>(base + (eh << 4));
      ar[2 * eh] = v.x; ai[2 * eh] = v.y; ar[2 * eh + 1] = v.z; ai[2 * eh + 1] = v.w;
    }
    // deferred wrapped CNOT_{L-1}: control 16-L+k, target k (k=0..L-1)
    static_for<L>([&](auto kc) {
      constexpr int k = kc.value;
      constexpr int C = 16 - L + k;
      if constexpr (k <= 3) cnot_local<k, 1, C>(ar, ai, ibase);
      else                  cnot_lane<1, C>(ar, ai, 1 << (k - 4), ibase);
    });
    // R_L(0..3) local, R_L(4..9) lane
    rot_local<0>(ar, ai, gl);
    rot_local<1>(ar, ai, gl + 8);
    rot_local<2>(ar, ai, gl + 16);
    rot_local<3>(ar, ai, gl + 24);
    #pragma unroll
    for (int q = 4; q <= 9; ++q)
      rot_lane(ar, ai, gl + q * 8, 1 << (q - 4), (tid >> (q - 4)) & 1);
  }

  // ring prefix g = 0..9-r, target t = g+r in [r, 9]
  static_for<10 - r>([&](auto gc) {
    constexpr int g = gc.value;
    constexpr int t = g + r;
    if constexpr (t <= 3) cnot_local<t, 1, g>(ar, ai, ibase);
    else                  cnot_lane<1, g>(ar, ai, 1 << (t - 4), ibase);
  });

  #pragma unroll
  for (int eh = 0; eh < 8; ++eh)
    *reinterpret_cast<float4*>(base + (eh << 4)) =
        make_float4(ar[2 * eh], ai[2 * eh], ar[2 * eh + 1], ai[2 * eh + 1]);
}

// ---------------- Sweep Q' : accessible {0,4,5,6,10..15} ----------------
template <int L>
__global__ void __launch_bounds__(NTH) sweepQ(float2* __restrict__ st,
                                              const float* __restrict__ gm) {
  const int tid = threadIdx.x;
  const int s  = blockIdx.x >> 3;
  const int fb = blockIdx.x & 7;
  // amp: e0=a0, e1-3=a10-12 | a4-6=tid0-2 | a13-15=tid3-5 | a7-9=tid6-8 | a1-3=fb
  const int ibase = ((tid & 7) << 4) | (((tid >> 3) & 7) << 13) |
                    (((tid >> 6) & 7) << 7) | (fb << 1);
  // phys: a4-6->p1-3, a1-3->p4-6, a10-12->p7-9(eh), a13-15->p10-12, a7-9->p13-15
  const int pbase = ((tid & 7) << 1) | (((tid >> 3) & 7) << 10) |
                    (((tid >> 6) & 7) << 13) | (fb << 4);
  float2* __restrict__ base = st + (s << 16) + pbase;
  constexpr int r = L + 1;
  const float* __restrict__ gl = gm + L * 128;
  v16f ar, ai;
  #pragma unroll
  for (int eh = 0; eh < 8; ++eh) {
    const float4 v = *reinterpret_cast<const float4*>(base + (eh << 7));
    ar[2 * eh] = v.x; ai[2 * eh] = v.y; ar[2 * eh + 1] = v.z; ai[2 * eh + 1] = v.w;
  }
  if constexpr (L > 0) {  // layer 0's rots were folded into init
    rot_local<1>(ar, ai, gl + 80);                    // R(10)
    rot_local<2>(ar, ai, gl + 88);                    // R(11)
    rot_local<3>(ar, ai, gl + 96);                    // R(12)
    rot_lane(ar, ai, gl + 104, 8,  (tid >> 3) & 1);   // R(13)
    rot_lane(ar, ai, gl + 112, 16, (tid >> 4) & 1);   // R(14)
    rot_lane(ar, ai, gl + 120, 32, (tid >> 5) & 1);   // R(15)
  }
  // ring mid g = 10-r .. 15-r, target t = g+r in [10,15]
  static_for<6>([&](auto gc) {
    constexpr int g = 10 - r + gc.value;
    constexpr int t = g + r;
    if constexpr (t >= 13) cnot_lane<10, g>(ar, ai, 1 << (t - 10), ibase);
    else                   cnot_local<t - 9, 10, g>(ar, ai, ibase);
  });

  #pragma unroll
  for (int eh = 0; eh < 8; ++eh)
    *reinterpret_cast<float4*>(base + (eh << 7)) =
        make_float4(ar[2 * eh], ai[2 * eh], ar[2 * eh + 1], ai[2 * eh + 1]);
}

// ---------------- final: 6 wrapped CNOT_5 + measurement (read-only) ----------------
__global__ void __launch_bounds__(NTH) finalK(const float2* __restrict__ st,
                                              float* __restrict__ part) {
  const int tid = threadIdx.x;
  const int s  = blockIdx.x >> 3;
  const int fb = blockIdx.x & 7;
  const int ibase = ((tid & 7) << 4) | (((tid >> 3) & 7) << 7) |
                    (((tid >> 6) & 7) << 10) | (fb << 13);
  const int pbase = ((tid & 7) << 1) | (((tid >> 6) & 7) << 7) | (fb << 10) |
                    (((tid >> 3) & 7) << 13);
  const float2* __restrict__ base = st + (s << 16) + pbase;
  v16f ar, ai;
  #pragma unroll
  for (int eh = 0; eh < 8; ++eh) {
    const float4 v = *reinterpret_cast<const float4*>(base + (eh << 4));
    ar[2 * eh] = v.x; ai[2 * eh] = v.y; ar[2 * eh + 1] = v.z; ai[2 * eh + 1] = v.w;
  }
  // deferred CNOT_5 (r=6): control 10+k, target k (k=0..5); controls are
  // wave bits (10-12) or fb bits (13-15) -> thread-uniform.
  static_for<6>([&](auto kc) {
    constexpr int k = kc.value;
    constexpr int C = 10 + k;
    if constexpr (k <= 3) cnot_local<k, 1, C>(ar, ai, ibase);
    else                  cnot_lane<1, C>(ar, ai, 1 << (k - 4), ibase);
  });
  // measurement: <Z_q> partials per block
  __shared__ float red[8][16];
  float tot = 0.f, sl0 = 0.f, sl1 = 0.f, sl2 = 0.f, sl3 = 0.f;
  static_for<16>([&](auto ec) {
    constexpr int e = ec.value;
    const float p = ar[e] * ar[e] + ai[e] * ai[e];
    tot += p;
    if constexpr (e & 1) sl0 -= p; else sl0 += p;
    if constexpr (e & 2) sl1 -= p; else sl1 += p;
    if constexpr (e & 4) sl2 -= p; else sl2 += p;
    if constexpr (e & 8) sl3 -= p; else sl3 += p;
  });
  const float sl[4] = {sl0, sl1, sl2, sl3};
  const int wv = tid >> 6;
  static_for<16>([&](auto qc) {
    constexpr int q = qc.value;
    float v;
    if constexpr (q < 4) v = sl[q];
    else v = ((ibase >> q) & 1) ? -tot : tot;
    v += __shfl_xor(v, 1);  v += __shfl_xor(v, 2);  v += __shfl_xor(v, 4);
    v += __shfl_xor(v, 8);  v += __shfl_xor(v, 16); v += __shfl_xor(v, 32);
    if ((tid & 63) == 0) red[wv][q] = v;
  });
  __syncthreads();
  if (tid < 16) {
    float a = 0.f;
    #pragma unroll
    for (int w8 = 0; w8 < 8; ++w8) a += red[w8][tid];
    part[blockIdx.x * 16 + tid] = a;
  }
}

// ---------------- final reduce: 8 block-partials -> out ----------------
__global__ void __launch_bounds__(NTH) reduceK(const float* __restrict__ part,
                                               float* __restrict__ out) {
  const int j = blockIdx.x * NTH + threadIdx.x;  // j = s*16 + q, j < 8192
  const int s = j >> 4, q = j & 15;
  float a = 0.f;
  #pragma unroll
  for (int fb = 0; fb < 8; ++fb) a += part[(s << 7) + fb * 16 + q];
  out[j] = a;
}

extern "C" void kernel_launch(void* const* d_in, const int* in_sizes, int n_in,
                              void* d_out, int out_size, void* d_ws, size_t ws_size,
                              hipStream_t stream) {
  (void)in_sizes; (void)n_in; (void)out_size;
  const float* x = (const float*)d_in[0];
  const float* w = (const float*)d_in[1];
  float* out = (float*)d_out;
  float* gm   = (float*)d_ws;                          // 768 floats
  float* part = (float*)((char*)d_ws + 4096);          // 512*8*16 floats = 256 KB
  float2* st  = (float2*)((char*)d_ws + 524288);       // state, chunked to fit ws

  const size_t avail = ws_size > 524288 ? ws_size - 524288 : 0;
  long long chunk = (long long)(avail / 524288);       // 512 KB per sample
  if (chunk > 256) chunk = 256;                        // 128 MB: L3-resident chunk
  if (chunk < 1) chunk = 1;

  qsim_prep<<<dim3(1), dim3(128), 0, stream>>>(w, gm);
  for (int s0 = 0; s0 < 512; s0 += (int)chunk) {
    const int ns = (512 - s0) < (int)chunk ? (512 - s0) : (int)chunk;
    const dim3 g(ns * 8), b(NTH);
    const float* xs = x + s0 * 16;
    float* pp = part + (size_t)s0 * 128;
    sweepP<0><<<g, b, 0, stream>>>(st, xs, gm);
    sweepQ<0><<<g, b, 0, stream>>>(st, gm);
    sweepP<1><<<g, b, 0, stream>>>(st, xs, gm);
    sweepQ<1><<<g, b, 0, stream>>>(st, gm);
    sweepP<2><<<g, b, 0, stream>>>(st, xs, gm);
    sweepQ<2><<<g, b, 0, stream>>>(st, gm);
    sweepP<3><<<g, b, 0, stream>>>(st, xs, gm);
    sweepQ<3><<<g, b, 0, stream>>>(st, gm);
    sweepP<4><<<g, b, 0, stream>>>(st, xs, gm);
    sweepQ<4><<<g, b, 0, stream>>>(st, gm);
    sweepP<5><<<g, b, 0, stream>>>(st, xs, gm);
    sweepQ<5><<<g, b, 0, stream>>>(st, gm);
    finalK<<<g, b, 0, stream>>>(st, pp);
  }
  reduceK<<<dim3(16), dim3(NTH), 0, stream>>>(part, out);
}